// Round 11
// baseline (713.878 us; speedup 1.0000x reference)
//
#include <hip/hip_runtime.h>

// ---------------------------------------------------------------------------
// FocalAtt (CA mode): B=8, Lq=512, Lk=1024, qd=kd=768, hid=1024, mid=4096,
// H=16, dh=64. Inputs f32, outputs f32. bf16 MFMA GEMMs (16x16x32), fp32 acc.
// R10: FFN re-chunked over M (not K): ff2 single-shot K=4096 (no f32 RMW,
// bias once, identical accumulation order); full W1T/W2T transposed once into
// the qq_out spare region; ff1 on 128x128 swizzled tiles (mgemm128).
// attout8 -> 4 elems/thread (grid 512).
// Workspace peak 58,241,024 B (< known-good 58,490,880).
// ---------------------------------------------------------------------------

typedef unsigned short bfr;  // raw bf16 bits
using short8 = __attribute__((ext_vector_type(8))) short;
using f32x4  = __attribute__((ext_vector_type(4))) float;

__device__ __forceinline__ float b2f(bfr s) {
  return __uint_as_float(((unsigned int)s) << 16);
}
__device__ __forceinline__ bfr f2b(float f) {
  unsigned int u = __float_as_uint(f);
  u += 0x7fffu + ((u >> 16) & 1u);  // RNE
  return (bfr)(u >> 16);
}

struct __align__(8) us4 { bfr x, y, z, w; };

__device__ __forceinline__ float4 load4f(const float* p) { return *(const float4*)p; }
__device__ __forceinline__ float4 load4f(const bfr* p) {
  us4 u = *(const us4*)p;
  return make_float4(b2f(u.x), b2f(u.y), b2f(u.z), b2f(u.w));
}
__device__ __forceinline__ void store4(float* p, float a, float b, float c, float d) {
  *(float4*)p = make_float4(a, b, c, d);
}
__device__ __forceinline__ void store4(bfr* p, float a, float b, float c, float d) {
  us4 v; v.x = f2b(a); v.y = f2b(b); v.z = f2b(c); v.w = f2b(d);
  *(us4*)p = v;
}

// async global(bf16 x8, 16B) -> LDS at wave-uniform base + lane*16B
__device__ __forceinline__ void gll16(const bfr* g, bfr* l) {
  __builtin_amdgcn_global_load_lds(
      (const __attribute__((address_space(1))) unsigned int*)g,
      (__attribute__((address_space(3))) unsigned int*)l, 16, 0, 0);
}

// element offset into a [rows][64-bf16] tile, chunk = 16B unit 0..7,
// XOR-swizzled: slot(r,c) = r*8 + (c ^ (r&7))  (bank-conflict-free reads)
__device__ __forceinline__ int swz_off(int row, int chunk) {
  return row * 64 + ((chunk ^ (row & 7)) * 8);
}

// ---------------------------------------------------------------------------
// Positional encoding
// ---------------------------------------------------------------------------
__device__ __forceinline__ float pe_val(int l, int d) {
  float ang = (float)l * expf((float)(d & ~1) * (-9.210340371976184f / 768.0f));
  return (d & 1) ? cosf(ang) : sinf(ang);
}

// k + PE -> f32 kp (output) AND bf16 copy (GEMM operand). total = 8*1024*768
__global__ __launch_bounds__(256) void posenc_k(const float* __restrict__ in,
                                                float* __restrict__ outf,
                                                bfr* __restrict__ outb, int total) {
  int idx = blockIdx.x * 256 + threadIdx.x;
  if (idx >= total) return;
  float v = in[idx] + pe_val((idx / 768) % 1024, idx % 768);
  outf[idx] = v;
  outb[idx] = f2b(v);
}

// q + PE -> bf16 qp_all [4096,768]; plain q -> bf16 q_b16
__global__ __launch_bounds__(256) void posenc_q_all(const float* __restrict__ in,
                                                    bfr* __restrict__ out,
                                                    bfr* __restrict__ outraw,
                                                    int total) {
  int idx = blockIdx.x * 256 + threadIdx.x;
  if (idx >= total) return;
  float v = in[idx];
  out[idx] = f2b(v + pe_val((idx / 768) % 512, idx % 768));
  outraw[idx] = f2b(v);
}

// ---------------------------------------------------------------------------
// Weight transpose: src f32 [rows, cols] (row stride ld) -> dst bf16 [cols, rows]
// grid (cols/32, rows/32), 256 threads. mode: dst-row remap for interleaved
// v1|v0 stacking. 0: r=c; 1: r=(c>>6)*128+(c&63); 2: r=(c>>6)*128+64+(c&63).
// ---------------------------------------------------------------------------
__global__ __launch_bounds__(256) void transpose_w(const float* __restrict__ src,
                                                   bfr* __restrict__ dst,
                                                   int rows, int cols, int ld,
                                                   int mode) {
  __shared__ float t[32][33];
  const int bc = blockIdx.x * 32, br = blockIdx.y * 32;
  const int tx = threadIdx.x & 31, ty = threadIdx.x >> 5;  // ty 0..7
#pragma unroll
  for (int i = 0; i < 4; i++)
    t[ty + i * 8][tx] = src[(size_t)(br + ty + i * 8) * ld + bc + tx];
  __syncthreads();
#pragma unroll
  for (int i = 0; i < 4; i++) {
    int c = bc + ty + i * 8;
    int r = (mode == 0) ? c : ((c >> 6) * 128 + (c & 63) + (mode == 2 ? 64 : 0));
    dst[(size_t)r * rows + br + tx] = f2b(t[tx][ty + i * 8]);
  }
}

// ---------------------------------------------------------------------------
// MFMA GEMM body, 128x64 tile: C[M,N] = A[M,K] @ B[K,N] (+bias, relu, accum).
// B passed as BT[N,K]. 4 waves (2m x 2n), each wave 64x32 = 4x2 fragments,
// BK=64. 2-deep: issue(t+1, buf^1) before MFMA(t); vmcnt(0)+barrier per step.
// 48 KB LDS -> 3 blocks/CU; inter-block overlap hides the drain (m114).
// Staging: global_load_lds w16, linear LDS dest, pre-swizzled global source
// chunk ((lane&7)^(lane>>3)); reads apply matching XOR (conflict-free).
// A-frag: lane holds A[m=lane&15][k=(lane>>4)*8+j]; D: row=(lane>>4)*4+r,
// col=lane&15 (measured m89/m91 layouts). K % 64 == 0, NT >= 2.
// ---------------------------------------------------------------------------
template <typename TC>
__device__ __forceinline__ void mgemm_body64(const bfr* __restrict__ A,
                                             const bfr* __restrict__ BT,
                                             const float* __restrict__ bias,
                                             TC* __restrict__ C,
                                             int K, int ldc, int relu, int accum,
                                             int m0, int n0,
                                             bfr* __restrict__ As,   // [2][8192]
                                             bfr* __restrict__ Bs) { // [2][4096]
  const int tid = threadIdx.x;
  const int lane = tid & 63, w = tid >> 6;
  const int wm = (w & 1) * 64, wn = (w >> 1) * 32;
  const int grow = lane >> 3;
  const int gkc = ((lane & 7) ^ (lane >> 3)) * 8;  // pre-swizzled source chunk
  const int fr = lane & 15, fcg = lane >> 4;
  const int NT = K >> 6;
  f32x4 acc[4][2];
#pragma unroll
  for (int i = 0; i < 4; i++)
#pragma unroll
    for (int j = 0; j < 2; j++) acc[i][j] = (f32x4){0.f, 0.f, 0.f, 0.f};

  auto issue = [&](int t, int buf) {  // 6 gll16 per wave
    const int k0 = t << 6;
    const bfr* Ag = A + (size_t)(m0 + w * 32 + grow) * K + k0 + gkc;
#pragma unroll
    for (int i = 0; i < 4; i++)
      gll16(Ag + (size_t)(i * 8) * K, As + buf * 8192 + (w * 32 + i * 8) * 64);
    const bfr* Bg = BT + (size_t)(n0 + w * 16 + grow) * K + k0 + gkc;
#pragma unroll
    for (int i = 0; i < 2; i++)
      gll16(Bg + (size_t)(i * 8) * K, Bs + buf * 4096 + (w * 16 + i * 8) * 64);
  };

  issue(0, 0);
  asm volatile("s_waitcnt vmcnt(0)" ::: "memory");
  __builtin_amdgcn_s_barrier();
  __builtin_amdgcn_sched_barrier(0);
  int cur = 0;
  for (int t = 0; t < NT; ++t) {
    const bool more = (t + 1 < NT);
    if (more) issue(t + 1, cur ^ 1);
    __builtin_amdgcn_s_setprio(1);
#pragma unroll
    for (int ks = 0; ks < 2; ks++) {
      short8 af[4], bf4[2];
#pragma unroll
      for (int i = 0; i < 4; i++)
        af[i] = *(const short8*)(As + cur * 8192 + swz_off(wm + i * 16 + fr, ks * 4 + fcg));
#pragma unroll
      for (int j = 0; j < 2; j++)
        bf4[j] = *(const short8*)(Bs + cur * 4096 + swz_off(wn + j * 16 + fr, ks * 4 + fcg));
#pragma unroll
      for (int i = 0; i < 4; i++)
#pragma unroll
        for (int j = 0; j < 2; j++)
          acc[i][j] = __builtin_amdgcn_mfma_f32_16x16x32_bf16(af[i], bf4[j], acc[i][j], 0, 0, 0);
    }
    __builtin_amdgcn_s_setprio(0);
    if (more) {
      asm volatile("s_waitcnt vmcnt(0)" ::: "memory");
      __builtin_amdgcn_s_barrier();
      __builtin_amdgcn_sched_barrier(0);
      cur ^= 1;
    }
  }
  const int col0 = n0 + wn + fr;
  const int row0 = m0 + wm + (lane >> 4) * 4;
  float bsv[2];
#pragma unroll
  for (int j = 0; j < 2; j++) bsv[j] = bias ? bias[col0 + j * 16] : 0.f;
#pragma unroll
  for (int i = 0; i < 4; i++) {
#pragma unroll
    for (int j = 0; j < 2; j++) {
      const int col = col0 + j * 16;
#pragma unroll
      for (int r = 0; r < 4; r++) {
        const int row = row0 + i * 16 + r;
        float v = acc[i][j][r] + bsv[j];
        if (relu) v = fmaxf(v, 0.f);
        size_t idx = (size_t)row * ldc + col;
        if constexpr (sizeof(TC) == 2) {
          C[idx] = f2b(v);
        } else {
          if (accum) C[idx] += v; else C[idx] = v;
        }
      }
    }
  }
}

// standalone 128x64-tile wrapper: 2-D grid, XCD-bijective swizzle (m204)
template <typename TC>
__global__ __launch_bounds__(256) void mgemm64(const bfr* __restrict__ A,
                                               const bfr* __restrict__ BT,
                                               const float* __restrict__ bias,
                                               TC* __restrict__ C,
                                               int K, int ldc, int relu, int accum) {
  __shared__ bfr As[2][8192];
  __shared__ bfr Bs[2][4096];
  const int nwg = gridDim.x * gridDim.y;
  const int bid = blockIdx.y * gridDim.x + blockIdx.x;
  const int q8 = nwg >> 3, r8 = nwg & 7;
  const int xcd = bid & 7, off = bid >> 3;
  const int swz = (xcd < r8 ? xcd * (q8 + 1) : r8 * (q8 + 1) + (xcd - r8) * q8) + off;
  const int n0 = (swz % gridDim.x) * 64, m0 = (swz / gridDim.x) * 128;
  mgemm_body64<TC>(A, BT, bias, C, K, ldc, relu, accum, m0, n0,
                   &As[0][0], &Bs[0][0]);
}

// ---------------------------------------------------------------------------
// 128x128-tile GEMM (big-GEMM path, e.g. ff1): 4 waves each 64x64 (4x4
// frags), BK=64, 2-deep dbuf, swizzled staging/reads, setprio. 64 KB LDS.
// ---------------------------------------------------------------------------
template <typename TC>
__global__ __launch_bounds__(256) void mgemm128(const bfr* __restrict__ A,
                                                const bfr* __restrict__ BT,
                                                const float* __restrict__ bias,
                                                TC* __restrict__ C,
                                                int K, int ldc, int relu, int accum) {
  __shared__ bfr As[2][8192];
  __shared__ bfr Bs[2][8192];
  const int nwg = gridDim.x * gridDim.y;
  const int bid = blockIdx.y * gridDim.x + blockIdx.x;
  const int q8 = nwg >> 3, r8 = nwg & 7;
  const int xcd = bid & 7, off = bid >> 3;
  const int swz = (xcd < r8 ? xcd * (q8 + 1) : r8 * (q8 + 1) + (xcd - r8) * q8) + off;
  const int n0 = (swz % gridDim.x) * 128, m0 = (swz / gridDim.x) * 128;
  const int tid = threadIdx.x;
  const int lane = tid & 63, w = tid >> 6;
  const int wm = (w & 1) * 64, wn = (w >> 1) * 64;
  const int grow = lane >> 3;
  const int gkc = ((lane & 7) ^ (lane >> 3)) * 8;  // pre-swizzled source chunk
  const int fr = lane & 15, fcg = lane >> 4;
  const int NT = K >> 6;
  f32x4 acc[4][4];
#pragma unroll
  for (int i = 0; i < 4; i++)
#pragma unroll
    for (int j = 0; j < 4; j++) acc[i][j] = (f32x4){0.f, 0.f, 0.f, 0.f};

  auto issue = [&](int t, int buf) {  // 8 gll16 per wave
    const int k0 = t << 6;
    const bfr* Ag = A + (size_t)(m0 + w * 32 + grow) * K + k0 + gkc;
#pragma unroll
    for (int i = 0; i < 4; i++)
      gll16(Ag + (size_t)(i * 8) * K, &As[buf][(w * 32 + i * 8) * 64]);
    const bfr* Bg = BT + (size_t)(n0 + w * 32 + grow) * K + k0 + gkc;
#pragma unroll
    for (int i = 0; i < 4; i++)
      gll16(Bg + (size_t)(i * 8) * K, &Bs[buf][(w * 32 + i * 8) * 64]);
  };

  issue(0, 0);
  asm volatile("s_waitcnt vmcnt(0)" ::: "memory");
  __builtin_amdgcn_s_barrier();
  __builtin_amdgcn_sched_barrier(0);
  int cur = 0;
  for (int t = 0; t < NT; ++t) {
    const bool more = (t + 1 < NT);
    if (more) issue(t + 1, cur ^ 1);
    __builtin_amdgcn_s_setprio(1);
#pragma unroll
    for (int ks = 0; ks < 2; ks++) {
      short8 af[4], bf4[4];
#pragma unroll
      for (int i = 0; i < 4; i++)
        af[i] = *(const short8*)&As[cur][swz_off(wm + i * 16 + fr, ks * 4 + fcg)];
#pragma unroll
      for (int j = 0; j < 4; j++)
        bf4[j] = *(const short8*)&Bs[cur][swz_off(wn + j * 16 + fr, ks * 4 + fcg)];
#pragma unroll
      for (int i = 0; i < 4; i++)
#pragma unroll
        for (int j = 0; j < 4; j++)
          acc[i][j] = __builtin_amdgcn_mfma_f32_16x16x32_bf16(af[i], bf4[j], acc[i][j], 0, 0, 0);
    }
    __builtin_amdgcn_s_setprio(0);
    if (more) {
      asm volatile("s_waitcnt vmcnt(0)" ::: "memory");
      __builtin_amdgcn_s_barrier();
      __builtin_amdgcn_sched_barrier(0);
      cur ^= 1;
    }
  }
  const int col0 = n0 + wn + fr;
  const int row0 = m0 + wm + (lane >> 4) * 4;
  float bsv[4];
#pragma unroll
  for (int j = 0; j < 4; j++) bsv[j] = bias ? bias[col0 + j * 16] : 0.f;
#pragma unroll
  for (int i = 0; i < 4; i++) {
#pragma unroll
    for (int j = 0; j < 4; j++) {
      const int col = col0 + j * 16;
#pragma unroll
      for (int r = 0; r < 4; r++) {
        const int row = row0 + i * 16 + r;
        float v = acc[i][j][r] + bsv[j];
        if (relu) v = fmaxf(v, 0.f);
        size_t idx = (size_t)row * ldc + col;
        if constexpr (sizeof(TC) == 2) {
          C[idx] = f2b(v);
        } else {
          if (accum) C[idx] += v; else C[idx] = v;
        }
      }
    }
  }
}

// batch-paired K/V projection: 768 blocks @128x64 tiles.
// blocks 0..127 kh0, 128..255 kh1, 256..511 vT0, 512..767 vT1.
__global__ __launch_bounds__(256) void kv_gemm2(const bfr* __restrict__ kp0,
                                                const bfr* __restrict__ kp1,
                                                const bfr* __restrict__ WkT,
                                                const float* __restrict__ bk,
                                                bfr* __restrict__ kh0,
                                                bfr* __restrict__ kh1,
                                                const bfr* __restrict__ WTvv,
                                                bfr* __restrict__ vT0,
                                                bfr* __restrict__ vT1) {
  __shared__ bfr As[2][8192];
  __shared__ bfr Bs[2][4096];
  const int swz = (blockIdx.x & 7) * 96 + (blockIdx.x >> 3);  // nwg=768, r8=0
  if (swz < 128) {          // kh0: M=1024 (8x128), N=1024 (16x64)
    mgemm_body64<bfr>(kp0, WkT, bk, kh0, 768, 1024, 0, 0,
                      (swz >> 4) * 128, (swz & 15) * 64, &As[0][0], &Bs[0][0]);
  } else if (swz < 256) {
    const int s = swz - 128;
    mgemm_body64<bfr>(kp1, WkT, bk, kh1, 768, 1024, 0, 0,
                      (s >> 4) * 128, (s & 15) * 64, &As[0][0], &Bs[0][0]);
  } else if (swz < 512) {   // vT0: M=2048 (16x128), N=1024 (16x64)
    const int s = swz - 256;
    mgemm_body64<bfr>(WTvv, kp0, nullptr, vT0, 768, 1024, 0, 0,
                      (s >> 4) * 128, (s & 15) * 64, &As[0][0], &Bs[0][0]);
  } else {
    const int s = swz - 512;
    mgemm_body64<bfr>(WTvv, kp1, nullptr, vT1, 768, 1024, 0, 0,
                      (s >> 4) * 128, (s & 15) * 64, &As[0][0], &Bs[0][0]);
  }
}

// fused q projections: blocks 0..511 -> q0p = q_b16@Wq0T + bq0 (32x16),
// blocks 512..1023 -> qh = qp_all@WqT + bq (32x16). 1-D grid 1024.
__global__ __launch_bounds__(256) void proj_gemm(const bfr* __restrict__ q16,
                                                 const bfr* __restrict__ Wq0T,
                                                 const float* __restrict__ bq0,
                                                 bfr* __restrict__ q0p,
                                                 const bfr* __restrict__ qp_all,
                                                 const bfr* __restrict__ WqT,
                                                 const float* __restrict__ bq,
                                                 bfr* __restrict__ qh) {
  __shared__ bfr As[2][8192];
  __shared__ bfr Bs[2][4096];
  const int swz = (blockIdx.x & 7) * 128 + (blockIdx.x >> 3);  // nwg=1024, r8=0
  if (swz < 512) {
    mgemm_body64<bfr>(q16, Wq0T, bq0, q0p, 768, 1024, 0, 0,
                      (swz >> 4) * 128, (swz & 15) * 64, &As[0][0], &Bs[0][0]);
  } else {
    const int s = swz - 512;
    mgemm_body64<bfr>(qp_all, WqT, bq, qh, 768, 1024, 0, 0,
                      (s >> 4) * 128, (s & 15) * 64, &As[0][0], &Bs[0][0]);
  }
}

// ---------------------------------------------------------------------------
// MFMA scores (one batch): sc[h,q,k] = dot_64(qh[q,h*64+:], kh[k,h*64+:]) / 8
// 128x128 tile, K=64 (two 32-steps, staged once). grid (8 kb, 4 qb, 16 h).
// ---------------------------------------------------------------------------
__global__ __launch_bounds__(256) void score_mfma(const bfr* __restrict__ qh,
                                                  const bfr* __restrict__ kh,
                                                  bfr* __restrict__ sc) {
  __shared__ __align__(16) bfr Qs[128][72];  // stride 144 B: 2-way max, free
  __shared__ __align__(16) bfr Ks[128][72];
  const int h = blockIdx.z, q0 = blockIdx.y * 128, k0 = blockIdx.x * 128;
  const int tid = threadIdx.x, lane = tid & 63;
  const int wm = ((tid >> 6) & 1) * 64, wn = (tid >> 7) * 64;
  const int fr = lane & 15, fc = (lane >> 4) * 8;
  {
    const int r = tid >> 1, c = (tid & 1) * 32;
    const bfr* qsrc = qh + (size_t)(q0 + r) * 1024 + h * 64 + c;
    const bfr* ksrc = kh + (size_t)(k0 + r) * 1024 + h * 64 + c;
#pragma unroll
    for (int i = 0; i < 4; i++) {
      *(short8*)&Qs[r][c + i * 8] = *(const short8*)(qsrc + i * 8);
      *(short8*)&Ks[r][c + i * 8] = *(const short8*)(ksrc + i * 8);
    }
  }
  __syncthreads();
  f32x4 acc[4][4];
#pragma unroll
  for (int i = 0; i < 4; i++)
#pragma unroll
    for (int j = 0; j < 4; j++) acc[i][j] = (f32x4){0.f, 0.f, 0.f, 0.f};
  __builtin_amdgcn_s_setprio(1);
#pragma unroll
  for (int ks = 0; ks < 2; ks++) {
    short8 af[4], bf[4];
#pragma unroll
    for (int t = 0; t < 4; t++) af[t] = *(const short8*)&Qs[wm + t * 16 + fr][ks * 32 + fc];
#pragma unroll
    for (int t = 0; t < 4; t++) bf[t] = *(const short8*)&Ks[wn + t * 16 + fr][ks * 32 + fc];
#pragma unroll
    for (int i = 0; i < 4; i++)
#pragma unroll
      for (int j = 0; j < 4; j++)
        acc[i][j] = __builtin_amdgcn_mfma_f32_16x16x32_bf16(af[i], bf[j], acc[i][j], 0, 0, 0);
  }
  __builtin_amdgcn_s_setprio(0);
  const int col0 = k0 + wn + fr;
  const int row0 = q0 + wm + (lane >> 4) * 4;
#pragma unroll
  for (int i = 0; i < 4; i++)
#pragma unroll
    for (int j = 0; j < 4; j++)
#pragma unroll
      for (int r = 0; r < 4; r++)
        sc[((size_t)h * 512 + row0 + i * 16 + r) * 1024 + col0 + j * 16] =
            f2b(acc[i][j][r] * 0.125f);
}

// ao-only pass: ao[q,k] = sum_h relu(sc[h,q,k])/16 (pre-softmax, f32 out).
// grid 512, 4 elems/thread.
__global__ __launch_bounds__(256) void attout4(const bfr* __restrict__ sc,
                                               float* __restrict__ ao) {
  const int i4 = (blockIdx.x * 256 + threadIdx.x) * 4;  // < 524288
  float s[4] = {};
#pragma unroll
  for (int h = 0; h < 16; h++) {
    us4 r = *(const us4*)(sc + (size_t)h * 524288 + i4);
    s[0] += fmaxf(b2f(r.x), 0.f); s[1] += fmaxf(b2f(r.y), 0.f);
    s[2] += fmaxf(b2f(r.z), 0.f); s[3] += fmaxf(b2f(r.w), 0.f);
  }
  store4(ao + i4, s[0] * 0.0625f, s[1] * 0.0625f, s[2] * 0.0625f, s[3] * 0.0625f);
}

// ---------------------------------------------------------------------------
// Fused softmax + att@V (one batch): block (qb of 16 rows, h), grid (32,16).
// Phase 1: read PRE-softmax sc rows (64 vals/thread, 16 thr/row), f32
// max/exp/sum via 16-lane shfl, write normalized bf16 P into padded LDS
// [16][1032]. Phase 2 = PV: 4 waves split d' (32 each): w0,w1 -> atp(+bv),
// w2,w3 -> u(+bv0); V dbuf via swizzled gll16, 2-deep. V tile 0 issued
// BEFORE phase 1 (latency hidden under softmax). Bias exact.
// LDS 65,792 B static -- legal on gfx950 (160 KiB/workgroup).
// ---------------------------------------------------------------------------
__global__ __launch_bounds__(256) void attv4(const bfr* __restrict__ sc,
                                             const bfr* __restrict__ vT,
                                             const float* __restrict__ bv,
                                             const float* __restrict__ bv0,
                                             bfr* __restrict__ atp,
                                             bfr* __restrict__ u) {
  __shared__ bfr attL[16][1032];   // 33 KB, row stride 2064 B
  __shared__ bfr Bs[2][128 * 64];  // 32 KB
  const int h = blockIdx.y, q0 = blockIdx.x * 16;
  const int tid = threadIdx.x, lane = tid & 63, w = tid >> 6;
  const int fr = lane & 15, fcg = lane >> 4;
  const int wn = w * 32;  // d' base for this wave
  const bfr* vb = vT + (size_t)h * 128 * 1024;
  const int grow = lane >> 3;
  const int gkc = ((lane & 7) ^ (lane >> 3)) * 8;  // pre-swizzled source chunk

  auto issueV = [&](int t, int buf) {
    const int k0 = t << 6;
#pragma unroll
    for (int i = 0; i < 4; i++)
      gll16(vb + (size_t)(wn + i * 8 + grow) * 1024 + k0 + gkc,
            &Bs[buf][(wn + i * 8) * 64]);
  };

  issueV(0, 0);  // V tile 0 in flight during softmax

  // ---- phase 1: softmax over the 1024-wide row q0+row ----
  const int row = tid >> 4, seg = tid & 15;
  const bfr* srow = sc + ((size_t)h * 512 + q0 + row) * 1024;
  short8 raw[8];
#pragma unroll
  for (int j = 0; j < 8; j++)
    raw[j] = *(const short8*)(srow + j * 128 + seg * 8);
  float v[64];
#pragma unroll
  for (int j = 0; j < 8; j++)
#pragma unroll
    for (int e = 0; e < 8; e++)
      v[j * 8 + e] = b2f((bfr)raw[j][e]);
  float m = v[0];
#pragma unroll
  for (int i = 1; i < 64; i++) m = fmaxf(m, v[i]);
#pragma unroll
  for (int o = 1; o < 16; o <<= 1) m = fmaxf(m, __shfl_xor(m, o, 64));
  float s = 0.f;
#pragma unroll
  for (int i = 0; i < 64; i++) { v[i] = expf(v[i] - m); s += v[i]; }
#pragma unroll
  for (int o = 1; o < 16; o <<= 1) s += __shfl_xor(s, o, 64);
  const float inv = 1.0f / s;
#pragma unroll
  for (int j = 0; j < 8; j++) {
    short8 pw;
#pragma unroll
    for (int e = 0; e < 8; e++) pw[e] = (short)f2b(v[j * 8 + e] * inv);
    *(short8*)&attL[row][j * 128 + seg * 8] = pw;
  }
  asm volatile("s_waitcnt vmcnt(0)" ::: "memory");  // V tile 0 landed
  __syncthreads();                                  // attL visible

  // ---- phase 2: PV ----
  f32x4 acc[2];
#pragma unroll
  for (int j = 0; j < 2; j++) acc[j] = (f32x4){0.f, 0.f, 0.f, 0.f};
  int cur = 0;
  for (int t = 0; t < 16; ++t) {
    const bool more = (t + 1 < 16);
    if (more) issueV(t + 1, cur ^ 1);
    __builtin_amdgcn_s_setprio(1);
#pragma unroll
    for (int ks = 0; ks < 2; ks++) {
      short8 af = *(const short8*)&attL[fr][(t << 6) + ks * 32 + fcg * 8];
#pragma unroll
      for (int j = 0; j < 2; j++) {
        short8 bf = *(const short8*)&Bs[cur][swz_off(wn + j * 16 + fr, ks * 4 + fcg)];
        acc[j] = __builtin_amdgcn_mfma_f32_16x16x32_bf16(af, bf, acc[j], 0, 0, 0);
      }
    }
    __builtin_amdgcn_s_setprio(0);
    if (more) {
      asm volatile("s_waitcnt vmcnt(0)" ::: "memory");
      __builtin_amdgcn_s_barrier();
      __builtin_amdgcn_sched_barrier(0);
      cur ^= 1;
    }
  }
  const int row0 = q0 + (lane >> 4) * 4;
  bfr* o = (w < 2) ? atp : u;
  const float* bias = (w < 2) ? bv : bv0;
  const int dbase = wn & 63;  // 0 or 32 within the selected output half
#pragma unroll
  for (int j = 0; j < 2; j++) {
    const int cm = dbase + j * 16 + fr;  // 0..63
    const float bb = bias[h * 64 + cm];
#pragma unroll
    for (int r = 0; r < 4; r++)
      o[(size_t)(row0 + r) * 1024 + h * 64 + cm] = f2b(acc[j][r] + bb);
  }
}

// pair-merged xpre: grid (4,8,2). xpre[b][c] += sum_64rows q0p_b ⊙ u_b.
// u buffers are at stride 1,048,576 elements (atp0,ub0,atp1,ub1 packed).
__global__ __launch_bounds__(256) void xpre2(const bfr* __restrict__ q0p0,
                                             const bfr* __restrict__ u0,
                                             float* __restrict__ xpre0) {
  const int c = blockIdx.x * 256 + threadIdx.x;
  const int r0 = blockIdx.y * 64;
  const int j = blockIdx.z;
  const bfr* qp = q0p0 + (size_t)j * 524288 + (size_t)r0 * 1024 + c;
  const bfr* up = u0 + (size_t)j * 1048576 + (size_t)r0 * 1024 + c;
  float s = 0.f;
#pragma unroll 8
  for (int r = 0; r < 64; r++)
    s = fmaf(b2f(qp[(size_t)r * 1024]), b2f(up[(size_t)r * 1024]), s);
  atomicAdd(&xpre0[j * 1024 + c], s);
}

// ln body shared by all LN variants
template <typename OT>
__device__ __forceinline__ void ln_body(float4 v, const float* ga, const float* be,
                                        OT* outp, int tid, float* sm) {
  float s = v.x + v.y + v.z + v.w;
  for (int o = 32; o; o >>= 1) s += __shfl_down(s, o, 64);
  if ((tid & 63) == 0) sm[tid >> 6] = s;
  __syncthreads();
  s = sm[0] + sm[1] + sm[2] + sm[3];
  float mean = s * (1.0f / 1024.0f);
  float d0 = v.x - mean, d1 = v.y - mean, d2 = v.z - mean, d3 = v.w - mean;
  float q = d0 * d0 + d1 * d1 + d2 * d2 + d3 * d3;
  __syncthreads();
  for (int o = 32; o; o >>= 1) q += __shfl_down(q, o, 64);
  if ((tid & 63) == 0) sm[tid >> 6] = q;
  __syncthreads();
  q = sm[0] + sm[1] + sm[2] + sm[3];
  float rs = 1.0f / (sqrtf(q * (1.0f / 1023.0f)) + 1e-6f);
  float4 g = *(const float4*)(ga + tid * 4);
  float4 bb = *(const float4*)(be + tid * 4);
  store4(outp, g.x * d0 * rs + bb.x, g.y * d1 * rs + bb.y,
         g.z * d2 * rs + bb.z, g.w * d3 * rs + bb.w);
}

// torch_ln over rows of 1024: a*(x-mean)/(sqrt(var_unbiased)+1e-6)+b, X (+Y)
template <typename TX, typename TY, typename OT>
__global__ __launch_bounds__(256) void ln_kernel(const TX* __restrict__ X,
                                                 const TY* __restrict__ Y,
                                                 const float* __restrict__ ga,
                                                 const float* __restrict__ be,
                                                 OT* __restrict__ out) {
  __shared__ float sm[4];
  const size_t row = blockIdx.x;
  const int tid = threadIdx.x;
  float4 v = load4f(X + row * 1024 + tid * 4);
  if (Y) {
    float4 w = load4f(Y + row * 1024 + tid * 4);
    v.x += w.x; v.y += w.y; v.z += w.z; v.w += w.w;
  }
  ln_body(v, ga, be, out + row * 1024 + tid * 4, tid, sm);
}

// pair-merged attention LN: grid 1024. atl_b = LN(q0p_b + atp_b).
// atp buffers at stride 1,048,576 elements.
__global__ __launch_bounds__(256) void ln2_kernel(const bfr* __restrict__ q0p0,
                                                  const bfr* __restrict__ atp0,
                                                  const float* __restrict__ ga,
                                                  const float* __restrict__ be,
                                                  bfr* __restrict__ atl0) {
  __shared__ float sm[4];
  const int row = blockIdx.x;
  const int b = row >> 9, r = row & 511;
  const int tid = threadIdx.x;
  float4 v = load4f(q0p0 + (size_t)b * 524288 + (size_t)r * 1024 + tid * 4);
  float4 w = load4f(atp0 + (size_t)b * 1048576 + (size_t)r * 1024 + tid * 4);
  v.x += w.x; v.y += w.y; v.z += w.z; v.w += w.w;
  ln_body(v, ga, be, atl0 + (size_t)b * 524288 + (size_t)r * 1024 + tid * 4, tid, sm);
}

// ---------------------------------------------------------------------------
extern "C" void kernel_launch(void* const* d_in, const int* in_sizes, int n_in,
                              void* d_out, int out_size, void* d_ws, size_t ws_size,
                              hipStream_t stream) {
  (void)in_sizes; (void)n_in; (void)out_size; (void)ws_size;
  const float* q   = (const float*)d_in[0];
  const float* k   = (const float*)d_in[1];
  const float* Wq  = (const float*)d_in[2];
  const float* bq  = (const float*)d_in[3];
  const float* Wk  = (const float*)d_in[4];
  const float* bk  = (const float*)d_in[5];
  const float* Wv  = (const float*)d_in[6];
  const float* bv  = (const float*)d_in[7];
  const float* Wv0 = (const float*)d_in[8];
  const float* bv0 = (const float*)d_in[9];
  const float* Wq0 = (const float*)d_in[10];
  const float* bq0 = (const float*)d_in[11];
  const float* nqa = (const float*)d_in[12];
  const float* nqb = (const float*)d_in[13];
  const float* nxa = (const float*)d_in[14];
  const float* nxb = (const float*)d_in[15];
  const float* W1  = (const float*)d_in[16];
  const float* b1  = (const float*)d_in[17];
  const float* W2  = (const float*)d_in[18];
  const float* b2  = (const float*)d_in[19];
  const float* nsa = (const float*)d_in[20];
  const float* nsb = (const float*)d_in[21];

  float* out = (float*)d_out;
  float* x_out  = out;                       // 8,192
  float* qq_out = out + 8192;                // 4,194,304 f32 (written LAST)
  float* kp_out = out + 4202496;             // 6,291,456
  float* ao_out = out + 10493952;            // 4,194,304
  // qq_out region doubles as scratch: kp16/vT1 during attention,
  // W1Tf/W2Tf during FFN (kp16 dead by then). Final LN overwrites last.
  bfr* kp16 = (bfr*)qq_out;                  // 12,582,912 B
  bfr* vT1  = kp16 + 6291456;                //  4,194,304 B (tail of qq_out)
  bfr* W1Tf = (bfr*)qq_out;                  //  8,388,608 B [4096,1024]
  bfr* W2Tf = W1Tf + 4194304;                //  8,388,608 B [1024,4096]

  char* base = (char*)d_ws;
  // persistent (attention phase)
  bfr* q0p   = (bfr*)(base + 0);            // 8,388,608  [4096,1024]
  bfr* qh    = (bfr*)(base + 8388608);      // 8,388,608  [4096,1024]
  bfr* atl   = (bfr*)(base + 16777216);     // 8,388,608  [4096,1024]
  bfr* WqT   = (bfr*)(base + 25165824);     // 1,572,864  [1024,768]
  bfr* Wq0T  = (bfr*)(base + 26738688);     // 1,572,864
  bfr* WTkv  = (bfr*)(base + 28311552);     // 4,718,592  [WkT 1024; vv-interleaved 2048][768]
  float* xpre = (float*)(base + 33030144);  //    32,768  [8,1024]
  char* S = base + 33062912;                // scratch region (25,165,824 B)
  // attention-loop overlay (batch-paired)
  bfr* sc    = (bfr*)(S + 0);               // 16,777,216 [16,512,1024]
  bfr* kh0   = (bfr*)(S + 16777216);        //  2,097,152 [1024,1024]
  bfr* kh1   = (bfr*)(S + 18874368);        //  2,097,152
  bfr* vT0   = (bfr*)(S + 20971520);        //  4,194,304 [16][128][1024] v1|v0
  // atpb/ub overlay the dead kh of the same batch (kh dead after its score)
  bfr* atp0  = (bfr*)(S + 16777216);        //  1,048,576 [512,1024]
  bfr* ub0   = (bfr*)(S + 17825792);        //  1,048,576
  bfr* atp1  = (bfr*)(S + 18874368);        //  1,048,576
  bfr* ub1   = (bfr*)(S + 19922944);        //  1,048,576
  // pre-loop overlay (dead before attention buffers first written)
  bfr* qp_all = (bfr*)(S + 0);              //  6,291,456 [4096,768]
  bfr* q16    = (bfr*)(S + 6291456);        //  6,291,456 [4096,768] plain q bf16
  // FFN-phase overlay (attention buffers dead; q0p/qh dead)
  bfr* ff1n  = (bfr*)(S + 0);               // 16,777,216 [2048,4096] per M-chunk
  float* ff2a = (float*)(base + 0);         // 16,777,216 [4096,1024] f32 (over q0p/qh)

  // --- setup ---
  posenc_k<<<24576, 256, 0, stream>>>(k, kp_out, kp16, 6291456);
  posenc_q_all<<<12288, 256, 0, stream>>>(q, qp_all, q16, 3145728);
  transpose_w<<<dim3(32, 24), 256, 0, stream>>>(Wq, WqT, 768, 1024, 1024, 0);
  transpose_w<<<dim3(32, 24), 256, 0, stream>>>(Wq0, Wq0T, 768, 1024, 1024, 0);
  transpose_w<<<dim3(32, 24), 256, 0, stream>>>(Wk, WTkv, 768, 1024, 1024, 0);
  transpose_w<<<dim3(32, 24), 256, 0, stream>>>(Wv, WTkv + 786432, 768, 1024, 1024, 1);
  transpose_w<<<dim3(32, 24), 256, 0, stream>>>(Wv0, WTkv + 786432, 768, 1024, 1024, 2);

  // full-batch projections (fused, MFMA)
  proj_gemm<<<1024, 256, 0, stream>>>(q16, Wq0T, bq0, q0p, qp_all, WqT, bq, qh);
  hipMemsetAsync(xpre, 0, 32768, stream);

  // --- per-batch-pair attention ---
  for (int p = 0; p < 4; p++) {
    const int b0 = 2 * p;
    kv_gemm2<<<768, 256, 0, stream>>>(kp16 + (size_t)b0 * 786432,
                                      kp16 + (size_t)(b0 + 1) * 786432,
                                      WTkv, bk, kh0, kh1,
                                      WTkv + 786432, vT0, vT1);
    for (int j = 0; j < 2; j++) {
      const int b = b0 + j;
      bfr* kh = j ? kh1 : kh0;
      bfr* vT = j ? vT1 : vT0;
      bfr* atpb = j ? atp1 : atp0;
      bfr* ub = j ? ub1 : ub0;
      score_mfma<<<dim3(8, 4, 16), 256, 0, stream>>>(qh + (size_t)b * 524288, kh, sc);
      attout4<<<512, 256, 0, stream>>>(sc, ao_out + (size_t)b * 524288);
      attv4<<<dim3(32, 16), 256, 0, stream>>>(sc, vT, bv, bv0, atpb, ub);
    }
    xpre2<<<dim3(4, 8, 2), 256, 0, stream>>>(q0p + (size_t)b0 * 524288, ub0,
                                             xpre + b0 * 1024);
    ln2_kernel<<<1024, 256, 0, stream>>>(q0p + (size_t)b0 * 524288, atp0,
                                         nqa, nqb, atl + (size_t)b0 * 524288);
  }

  // x = LN(bilinear)
  ln_kernel<float, float, float><<<8, 256, 0, stream>>>(xpre, (const float*)nullptr,
                                                        nxa, nxb, x_out);

  // --- FFN, M-chunked (2 x 2048 rows); full weights transposed once into
  // the qq_out spare (kp16/vT1 dead). ff2 single-shot K=4096, no f32 RMW. ---
  transpose_w<<<dim3(128, 32), 256, 0, stream>>>(W1, W1Tf, 1024, 4096, 4096, 0);
  transpose_w<<<dim3(32, 128), 256, 0, stream>>>(W2, W2Tf, 4096, 1024, 1024, 0);
  for (int mc = 0; mc < 2; mc++) {
    mgemm128<bfr><<<dim3(32, 16), 256, 0, stream>>>(
        atl + (size_t)mc * 2097152, W1Tf, b1, ff1n, 1024, 4096, 1, 0);
    mgemm64<float><<<dim3(16, 16), 256, 0, stream>>>(
        ff1n, W2Tf, b2, ff2a + (size_t)mc * 2097152, 4096, 1024, 0, 0);
  }
  ln_kernel<bfr, float, float><<<4096, 256, 0, stream>>>(atl, ff2a, nsa, nsb, qq_out);
}